// Round 2
// baseline (452.218 us; speedup 1.0000x reference)
//
#include <hip/hip_runtime.h>
#include <hip/hip_bf16.h>

// N=1536 T=20 H=64 E=16 M=128
// pre1[i,j] = Q[j] - P[i]  (Q,P: N x 128 fp32, precomputed in d_ws ~1.57MB)
// out[i]    = max_j relu( relu(Q[j]-P[i]) @ W2 + b2 )

#define NN 1536
#define HH 64
#define EE 16
#define MM 128
#define TT 20
#define JSPLIT 4   // R1: 2 -> 4. 768 blocks (3/CU, 37% occ cap) was the limiter; 1536 -> 6/CU.

typedef __attribute__((ext_vector_type(8))) short short8;
typedef __attribute__((ext_vector_type(4))) float f32x4;

__device__ __forceinline__ unsigned pack_bf16_trunc(float lo, float hi) {
  // dst = { hi16(hi) , hi16(lo) } -> shorts [lo_bf16, hi_bf16]
  return __builtin_amdgcn_perm(__float_as_uint(hi), __float_as_uint(lo), 0x07060302u);
}

__device__ __forceinline__ short f2bf_rne(float f) {
  unsigned u = __float_as_uint(f);
  u += 0x7fffu + ((u >> 16) & 1u);
  return (short)(u >> 16);
}

// grid NN, block 128. Computes Q,P and zero-inits out (harness poisons it 0xAA).
__global__ __launch_bounds__(128) void precompute_kernel(
    const float* __restrict__ hidden, const float* __restrict__ gt,
    const float* __restrict__ We, const float* __restrict__ be,
    const float* __restrict__ W1, const float* __restrict__ b1,
    float* __restrict__ Q, float* __restrict__ P, float* __restrict__ out)
{
  const int j = blockIdx.x;
  const int m = threadIdx.x;
  const float* hrow = hidden + j * HH;
  float a = 0.f;
  #pragma unroll 8
  for (int h = 0; h < HH; ++h) a = fmaf(hrow[h], W1[h * MM + m], a);
  float ve0 = 0.f, ve1 = 0.f, cm = b1[m];
  #pragma unroll
  for (int e = 0; e < EE; ++e) {
    float w1e = W1[(HH + e) * MM + m];
    ve0 = fmaf(We[e], w1e, ve0);       // We[0][e]
    ve1 = fmaf(We[EE + e], w1e, ve1);  // We[1][e]
    cm  = fmaf(be[e], w1e, cm);
  }
  const float e0 = gt[j * (2 * TT) + 2 * (TT - 1)];
  const float e1 = gt[j * (2 * TT) + 2 * (TT - 1) + 1];
  const float p = fmaf(e0, ve0, e1 * ve1);
  P[j * MM + m] = p;
  Q[j * MM + m] = a + p + cm;
  if (m < HH) out[j * HH + m] = 0.f;
}

// grid (NN/4)*JSPLIT, block 256 (4 waves). Wave w -> i = ib*4+w, all 64 out cols.
// __launch_bounds__(256,6): pin VGPR <= 85 so HW occupancy cap stays 6 waves/SIMD (was 80 VGPR).
__global__ __launch_bounds__(256, 6) void pairmlp_max_kernel(
    const float* __restrict__ Q, const float* __restrict__ P,
    const float* __restrict__ W2, const float* __restrict__ b2,
    float* __restrict__ out)
{
  const int wave = threadIdx.x >> 6;
  const int lane = threadIdx.x & 63;
  const int quad = lane >> 4;   // 0..3
  const int lcol = lane & 15;
  const int ib = blockIdx.x % (NN / 4);
  const int js = blockIdx.x / (NN / 4);
  const int i  = ib * 4 + wave;

  // B fragments: W2 (128x64) -> 4 col-tiles x 4 k-steps, B[k=ks*32+quad*8+jj][n=ct*16+lcol]
  short8 bfrag[4][4];
  float b2v[4];
  #pragma unroll
  for (int ct = 0; ct < 4; ++ct) {
    const int col = ct * 16 + lcol;
    b2v[ct] = b2[col];
    #pragma unroll
    for (int ks = 0; ks < 4; ++ks) {
      short8 b;
      #pragma unroll
      for (int jj = 0; jj < 8; ++jj) {
        const int k = ks * 32 + quad * 8 + jj;
        b[jj] = f2bf_rne(W2[k * HH + col]);
      }
      bfrag[ct][ks] = b;
    }
  }

  // P[i] columns this lane needs for its A-fragment k-slots (fp32, 32 regs)
  f32x4 pv[4][2];
  const float* prow = P + i * MM;
  #pragma unroll
  for (int ks = 0; ks < 4; ++ks) {
    const float* pp = prow + ks * 32 + quad * 8;
    pv[ks][0] = *(const f32x4*)(pp);
    pv[ks][1] = *(const f32x4*)(pp + 4);
  }

  float rmax[4] = {0.f, 0.f, 0.f, 0.f};

  const int jt0 = js * (96 / JSPLIT);
  const int jt1 = jt0 + (96 / JSPLIT);
  for (int jt = jt0; jt < jt1; ++jt) {
    // A row m = lcol -> j row (jt*16 + lcol); per-lane 8 contiguous k's
    const float* qrow = Q + (jt * 16 + lcol) * MM;
    f32x4 acc[4];
    #pragma unroll
    for (int ct = 0; ct < 4; ++ct) acc[ct] = f32x4{0.f, 0.f, 0.f, 0.f};

    #pragma unroll
    for (int ks = 0; ks < 4; ++ks) {
      const float* qp = qrow + ks * 32 + quad * 8;
      f32x4 q0 = *(const f32x4*)(qp);
      f32x4 q1 = *(const f32x4*)(qp + 4);
      f32x4 s0 = q0 - pv[ks][0];
      f32x4 s1 = q1 - pv[ks][1];
      const float t0 = fmaxf(s0[0], 0.f), t1 = fmaxf(s0[1], 0.f);
      const float t2 = fmaxf(s0[2], 0.f), t3 = fmaxf(s0[3], 0.f);
      const float t4 = fmaxf(s1[0], 0.f), t5 = fmaxf(s1[1], 0.f);
      const float t6 = fmaxf(s1[2], 0.f), t7 = fmaxf(s1[3], 0.f);
      union { short8 v; unsigned u[4]; } af;
      af.u[0] = pack_bf16_trunc(t0, t1);
      af.u[1] = pack_bf16_trunc(t2, t3);
      af.u[2] = pack_bf16_trunc(t4, t5);
      af.u[3] = pack_bf16_trunc(t6, t7);
      #pragma unroll
      for (int ct = 0; ct < 4; ++ct)
        acc[ct] = __builtin_amdgcn_mfma_f32_16x16x32_bf16(af.v, bfrag[ct][ks], acc[ct], 0, 0, 0);
    }

    // C/D: col = lcol (+ct*16), row(j) = quad*4 + reg. rmax >= 0 so relu folds into fmax.
    #pragma unroll
    for (int ct = 0; ct < 4; ++ct) {
      const float m01 = fmaxf(acc[ct][0], acc[ct][1]);
      const float m23 = fmaxf(acc[ct][2], acc[ct][3]);
      rmax[ct] = fmaxf(rmax[ct], fmaxf(m01, m23) + b2v[ct]);
    }
  }

  // combine the 4 quad-groups (different j rows, same col), then atomic max (v >= 0)
  #pragma unroll
  for (int ct = 0; ct < 4; ++ct) {
    float v = rmax[ct];
    v = fmaxf(v, __shfl_xor(v, 16, 64));
    v = fmaxf(v, __shfl_xor(v, 32, 64));
    if (quad == 0)
      atomicMax((unsigned*)(out + i * HH + ct * 16 + lcol), __float_as_uint(v));
  }
}

extern "C" void kernel_launch(void* const* d_in, const int* in_sizes, int n_in,
                              void* d_out, int out_size, void* d_ws, size_t ws_size,
                              hipStream_t stream) {
  const float* hidden = (const float*)d_in[0];
  const float* gt     = (const float*)d_in[1];
  const float* We     = (const float*)d_in[2];
  const float* be     = (const float*)d_in[3];
  const float* W1     = (const float*)d_in[4];
  const float* b1     = (const float*)d_in[5];
  const float* W2     = (const float*)d_in[6];
  const float* b2     = (const float*)d_in[7];
  float* out = (float*)d_out;

  float* Q = (float*)d_ws;            // NN*MM fp32
  float* P = Q + NN * MM;             // NN*MM fp32  (total ~1.57 MB of d_ws)

  precompute_kernel<<<NN, 128, 0, stream>>>(hidden, gt, We, be, W1, b1, Q, P, out);
  pairmlp_max_kernel<<<(NN / 4) * JSPLIT, 256, 0, stream>>>(Q, P, W2, b2, out);
}

// Round 3
// 203.917 us; speedup vs baseline: 2.2177x; 2.2177x over previous
//
#include <hip/hip_runtime.h>
#include <hip/hip_bf16.h>

// N=1536 T=20 H=64 E=16 M=128
// pre1[i,j] = Q[j] - P[i]  (Q,P: N x 128 fp32, precomputed in d_ws ~1.57MB)
// out[i]    = max_j relu( relu(Q[j]-P[i]) @ W2 + b2 )

#define NN 1536
#define HH 64
#define EE 16
#define MM 128
#define TT 20
#define JSPLIT 4   // R2: 1536 blocks = 6 blocks/CU (R1's 768 = 3/CU capped occupancy at 30%).

typedef __attribute__((ext_vector_type(8))) short short8;
typedef __attribute__((ext_vector_type(4))) float f32x4;

__device__ __forceinline__ unsigned pack_bf16_trunc(float lo, float hi) {
  // dst = { hi16(hi) , hi16(lo) } -> shorts [lo_bf16, hi_bf16]
  return __builtin_amdgcn_perm(__float_as_uint(hi), __float_as_uint(lo), 0x07060302u);
}

__device__ __forceinline__ short f2bf_rne(float f) {
  unsigned u = __float_as_uint(f);
  u += 0x7fffu + ((u >> 16) & 1u);
  return (short)(u >> 16);
}

// grid NN, block 128. Computes Q,P and zero-inits out (harness poisons it 0xAA).
__global__ __launch_bounds__(128) void precompute_kernel(
    const float* __restrict__ hidden, const float* __restrict__ gt,
    const float* __restrict__ We, const float* __restrict__ be,
    const float* __restrict__ W1, const float* __restrict__ b1,
    float* __restrict__ Q, float* __restrict__ P, float* __restrict__ out)
{
  const int j = blockIdx.x;
  const int m = threadIdx.x;
  const float* hrow = hidden + j * HH;
  float a = 0.f;
  #pragma unroll 8
  for (int h = 0; h < HH; ++h) a = fmaf(hrow[h], W1[h * MM + m], a);
  float ve0 = 0.f, ve1 = 0.f, cm = b1[m];
  #pragma unroll
  for (int e = 0; e < EE; ++e) {
    float w1e = W1[(HH + e) * MM + m];
    ve0 = fmaf(We[e], w1e, ve0);       // We[0][e]
    ve1 = fmaf(We[EE + e], w1e, ve1);  // We[1][e]
    cm  = fmaf(be[e], w1e, cm);
  }
  const float e0 = gt[j * (2 * TT) + 2 * (TT - 1)];
  const float e1 = gt[j * (2 * TT) + 2 * (TT - 1) + 1];
  const float p = fmaf(e0, ve0, e1 * ve1);
  P[j * MM + m] = p;
  Q[j * MM + m] = a + p + cm;
  if (m < HH) out[j * HH + m] = 0.f;
}

// grid (NN/4)*JSPLIT, block 256 (4 waves). Wave w -> i = ib*4+w, all 64 out cols.
// __launch_bounds__(256,3): R2 lesson — (256,6) caps VGPR at 85, forces spills
// (VGPR 80->40, FETCH 3.6MB->1GB, 410us). Compiler's natural 80 VGPR already
// permits 6 waves/SIMD; do NOT squeeze the allocator.
__global__ __launch_bounds__(256, 3) void pairmlp_max_kernel(
    const float* __restrict__ Q, const float* __restrict__ P,
    const float* __restrict__ W2, const float* __restrict__ b2,
    float* __restrict__ out)
{
  const int wave = threadIdx.x >> 6;
  const int lane = threadIdx.x & 63;
  const int quad = lane >> 4;   // 0..3
  const int lcol = lane & 15;
  const int ib = blockIdx.x % (NN / 4);
  const int js = blockIdx.x / (NN / 4);
  const int i  = ib * 4 + wave;

  // B fragments: W2 (128x64) -> 4 col-tiles x 4 k-steps, B[k=ks*32+quad*8+jj][n=ct*16+lcol]
  short8 bfrag[4][4];
  float b2v[4];
  #pragma unroll
  for (int ct = 0; ct < 4; ++ct) {
    const int col = ct * 16 + lcol;
    b2v[ct] = b2[col];
    #pragma unroll
    for (int ks = 0; ks < 4; ++ks) {
      short8 b;
      #pragma unroll
      for (int jj = 0; jj < 8; ++jj) {
        const int k = ks * 32 + quad * 8 + jj;
        b[jj] = f2bf_rne(W2[k * HH + col]);
      }
      bfrag[ct][ks] = b;
    }
  }

  // P[i] columns this lane needs for its A-fragment k-slots (fp32, 32 regs)
  f32x4 pv[4][2];
  const float* prow = P + i * MM;
  #pragma unroll
  for (int ks = 0; ks < 4; ++ks) {
    const float* pp = prow + ks * 32 + quad * 8;
    pv[ks][0] = *(const f32x4*)(pp);
    pv[ks][1] = *(const f32x4*)(pp + 4);
  }

  float rmax[4] = {0.f, 0.f, 0.f, 0.f};

  const int jt0 = js * (96 / JSPLIT);
  const int jt1 = jt0 + (96 / JSPLIT);
  for (int jt = jt0; jt < jt1; ++jt) {
    // A row m = lcol -> j row (jt*16 + lcol); per-lane 8 contiguous k's
    const float* qrow = Q + (jt * 16 + lcol) * MM;
    f32x4 acc[4];
    #pragma unroll
    for (int ct = 0; ct < 4; ++ct) acc[ct] = f32x4{0.f, 0.f, 0.f, 0.f};

    #pragma unroll
    for (int ks = 0; ks < 4; ++ks) {
      const float* qp = qrow + ks * 32 + quad * 8;
      f32x4 q0 = *(const f32x4*)(qp);
      f32x4 q1 = *(const f32x4*)(qp + 4);
      f32x4 s0 = q0 - pv[ks][0];
      f32x4 s1 = q1 - pv[ks][1];
      const float t0 = fmaxf(s0[0], 0.f), t1 = fmaxf(s0[1], 0.f);
      const float t2 = fmaxf(s0[2], 0.f), t3 = fmaxf(s0[3], 0.f);
      const float t4 = fmaxf(s1[0], 0.f), t5 = fmaxf(s1[1], 0.f);
      const float t6 = fmaxf(s1[2], 0.f), t7 = fmaxf(s1[3], 0.f);
      union { short8 v; unsigned u[4]; } af;
      af.u[0] = pack_bf16_trunc(t0, t1);
      af.u[1] = pack_bf16_trunc(t2, t3);
      af.u[2] = pack_bf16_trunc(t4, t5);
      af.u[3] = pack_bf16_trunc(t6, t7);
      #pragma unroll
      for (int ct = 0; ct < 4; ++ct)
        acc[ct] = __builtin_amdgcn_mfma_f32_16x16x32_bf16(af.v, bfrag[ct][ks], acc[ct], 0, 0, 0);
    }

    // C/D: col = lcol (+ct*16), row(j) = quad*4 + reg. rmax >= 0 so relu folds into fmax.
    #pragma unroll
    for (int ct = 0; ct < 4; ++ct) {
      const float m01 = fmaxf(acc[ct][0], acc[ct][1]);
      const float m23 = fmaxf(acc[ct][2], acc[ct][3]);
      rmax[ct] = fmaxf(rmax[ct], fmaxf(m01, m23) + b2v[ct]);
    }
  }

  // combine the 4 quad-groups (different j rows, same col), then atomic max (v >= 0)
  #pragma unroll
  for (int ct = 0; ct < 4; ++ct) {
    float v = rmax[ct];
    v = fmaxf(v, __shfl_xor(v, 16, 64));
    v = fmaxf(v, __shfl_xor(v, 32, 64));
    if (quad == 0)
      atomicMax((unsigned*)(out + i * HH + ct * 16 + lcol), __float_as_uint(v));
  }
}

extern "C" void kernel_launch(void* const* d_in, const int* in_sizes, int n_in,
                              void* d_out, int out_size, void* d_ws, size_t ws_size,
                              hipStream_t stream) {
  const float* hidden = (const float*)d_in[0];
  const float* gt     = (const float*)d_in[1];
  const float* We     = (const float*)d_in[2];
  const float* be     = (const float*)d_in[3];
  const float* W1     = (const float*)d_in[4];
  const float* b1     = (const float*)d_in[5];
  const float* W2     = (const float*)d_in[6];
  const float* b2     = (const float*)d_in[7];
  float* out = (float*)d_out;

  float* Q = (float*)d_ws;            // NN*MM fp32
  float* P = Q + NN * MM;             // NN*MM fp32  (total ~1.57 MB of d_ws)

  precompute_kernel<<<NN, 128, 0, stream>>>(hidden, gt, We, be, W1, b1, Q, P, out);
  pairmlp_max_kernel<<<(NN / 4) * JSPLIT, 256, 0, stream>>>(Q, P, W2, b2, out);
}

// Round 4
// 109.989 us; speedup vs baseline: 4.1115x; 1.8540x over previous
//
#include <hip/hip_runtime.h>
#include <hip/hip_fp16.h>

// N=1536 T=20 H=64 E=16 M=128
// pre1[i,j] = Q[j] - P[i]  (Q,P: N x 128 fp16 in d_ws, 768KB)
// out[i]    = max_j relu( relu(Q[j]-P[i]) @ W2 + b2 )
//
// R4 design: fp16 end-to-end. packed sub/max builds the MFMA A-frag directly
// (no bf16 trunc-pack), Ni=3 i's per wave triples MFMA per staged byte,
// 1-wave blocks, grid 2048 = exactly 8 waves/CU (2/SIMD at ~230 VGPR), no tail.

#define NN 1536
#define HH 64
#define EE 16
#define MM 128
#define TT 20
#define NI 3
#define JSPLIT 4
#define NIGRP (NN / NI)      // 512 i-groups
#define NTILE (96 / JSPLIT)  // 24 j-tiles of 16 per wave

typedef _Float16 half8 __attribute__((ext_vector_type(8)));
typedef float f32x4 __attribute__((ext_vector_type(4)));

// grid NN, block 128. Computes Q,P (fp16) and zero-inits out (harness poisons 0xAA).
__global__ __launch_bounds__(128) void precompute_kernel(
    const float* __restrict__ hidden, const float* __restrict__ gt,
    const float* __restrict__ We, const float* __restrict__ be,
    const float* __restrict__ W1, const float* __restrict__ b1,
    _Float16* __restrict__ Q, _Float16* __restrict__ P, float* __restrict__ out)
{
  const int j = blockIdx.x;
  const int m = threadIdx.x;
  const float* hrow = hidden + j * HH;
  float a = 0.f;
  #pragma unroll 8
  for (int h = 0; h < HH; ++h) a = fmaf(hrow[h], W1[h * MM + m], a);
  float ve0 = 0.f, ve1 = 0.f, cm = b1[m];
  #pragma unroll
  for (int e = 0; e < EE; ++e) {
    float w1e = W1[(HH + e) * MM + m];
    ve0 = fmaf(We[e], w1e, ve0);       // We[0][e]
    ve1 = fmaf(We[EE + e], w1e, ve1);  // We[1][e]
    cm  = fmaf(be[e], w1e, cm);
  }
  const float e0 = gt[j * (2 * TT) + 2 * (TT - 1)];
  const float e1 = gt[j * (2 * TT) + 2 * (TT - 1) + 1];
  const float p = fmaf(e0, ve0, e1 * ve1);
  P[j * MM + m] = (_Float16)p;
  Q[j * MM + m] = (_Float16)(a + p + cm);
  if (m < HH) out[j * HH + m] = 0.f;
}

// grid NIGRP*JSPLIT (=2048), block 64 (1 wave). Wave: i0..i0+2, 24 j-tiles.
// __launch_bounds__(64,2): combined VGPR+AGPR cap 256; estimated live ~230.
__global__ __launch_bounds__(64, 2) void pairmlp_max_kernel(
    const _Float16* __restrict__ Q, const _Float16* __restrict__ P,
    const float* __restrict__ W2, const float* __restrict__ b2,
    float* __restrict__ out)
{
  const int lane = threadIdx.x;
  const int quad = lane >> 4;   // 0..3
  const int lcol = lane & 15;
  const int ig = blockIdx.x % NIGRP;
  const int js = blockIdx.x / NIGRP;
  const int i0 = ig * NI;

  // B fragments: W2 (128x64 fp32) -> fp16, B[k=ks*32+quad*8+jj][n=ct*16+lcol]
  half8 bfrag[4][4];
  float b2v[4];
  #pragma unroll
  for (int ct = 0; ct < 4; ++ct) {
    const int col = ct * 16 + lcol;
    b2v[ct] = b2[col];
    #pragma unroll
    for (int ks = 0; ks < 4; ++ks) {
      half8 b;
      #pragma unroll
      for (int jj = 0; jj < 8; ++jj)
        b[jj] = (_Float16)W2[(ks * 32 + quad * 8 + jj) * HH + col];
      bfrag[ct][ks] = b;
    }
  }

  // P fragments for NI i's: lane's A-frag k-slots (8 halfs per ks), fp16
  half8 pv[NI][4];
  #pragma unroll
  for (int ii = 0; ii < NI; ++ii) {
    const _Float16* prow = P + (i0 + ii) * MM + quad * 8;
    #pragma unroll
    for (int ks = 0; ks < 4; ++ks)
      pv[ii][ks] = *(const half8*)(prow + ks * 32);
  }

  float rmax[NI][4];
  #pragma unroll
  for (int ii = 0; ii < NI; ++ii)
    #pragma unroll
    for (int ct = 0; ct < 4; ++ct) rmax[ii][ct] = 0.f;

  const int jt0 = js * NTILE;
  const _Float16* qbase = Q + lcol * MM + quad * 8;  // + jt*16*MM + ks*32

  // prefetch first tile
  half8 qc[4], qn[4];
  #pragma unroll
  for (int ks = 0; ks < 4; ++ks)
    qc[ks] = *(const half8*)(qbase + (jt0 * 16) * MM + ks * 32);

  const half8 hz = 0;  // splat zero

  for (int t = 0; t < NTILE; ++t) {
    // prefetch next tile (clamped dummy on last iter; data unused)
    const int jl = (t + 1 < NTILE) ? (jt0 + t + 1) : jt0;
    #pragma unroll
    for (int ks = 0; ks < 4; ++ks)
      qn[ks] = *(const half8*)(qbase + (jl * 16) * MM + ks * 32);

    f32x4 acc[NI][4];
    #pragma unroll
    for (int ii = 0; ii < NI; ++ii)
      #pragma unroll
      for (int ct = 0; ct < 4; ++ct) acc[ii][ct] = f32x4{0.f, 0.f, 0.f, 0.f};

    #pragma unroll
    for (int ks = 0; ks < 4; ++ks) {
      #pragma unroll
      for (int ii = 0; ii < NI; ++ii) {
        // A-frag = relu(q - p) as packed fp16 (v_pk_sub_f16 / v_pk_max_f16)
        half8 s = qc[ks] - pv[ii][ks];
        s = __builtin_elementwise_max(s, hz);
        #pragma unroll
        for (int ct = 0; ct < 4; ++ct)
          acc[ii][ct] = __builtin_amdgcn_mfma_f32_16x16x32_f16(s, bfrag[ct][ks], acc[ii][ct], 0, 0, 0);
      }
    }

    // C/D: col=lcol(+ct*16), row(j)=quad*4+reg. rmax>=0 so relu folds into fmax.
    #pragma unroll
    for (int ii = 0; ii < NI; ++ii)
      #pragma unroll
      for (int ct = 0; ct < 4; ++ct) {
        const float m01 = fmaxf(acc[ii][ct][0], acc[ii][ct][1]);
        const float m23 = fmaxf(acc[ii][ct][2], acc[ii][ct][3]);
        rmax[ii][ct] = fmaxf(rmax[ii][ct], fmaxf(m01, m23) + b2v[ct]);
      }

    #pragma unroll
    for (int ks = 0; ks < 4; ++ks) qc[ks] = qn[ks];
  }

  // combine the 4 quad-groups (different j rows, same col), then atomic max (v >= 0)
  #pragma unroll
  for (int ii = 0; ii < NI; ++ii)
    #pragma unroll
    for (int ct = 0; ct < 4; ++ct) {
      float v = rmax[ii][ct];
      v = fmaxf(v, __shfl_xor(v, 16, 64));
      v = fmaxf(v, __shfl_xor(v, 32, 64));
      if (quad == 0)
        atomicMax((unsigned*)(out + (i0 + ii) * HH + ct * 16 + lcol), __float_as_uint(v));
    }
}

extern "C" void kernel_launch(void* const* d_in, const int* in_sizes, int n_in,
                              void* d_out, int out_size, void* d_ws, size_t ws_size,
                              hipStream_t stream) {
  const float* hidden = (const float*)d_in[0];
  const float* gt     = (const float*)d_in[1];
  const float* We     = (const float*)d_in[2];
  const float* be     = (const float*)d_in[3];
  const float* W1     = (const float*)d_in[4];
  const float* b1     = (const float*)d_in[5];
  const float* W2     = (const float*)d_in[6];
  const float* b2     = (const float*)d_in[7];
  float* out = (float*)d_out;

  _Float16* Qh = (_Float16*)d_ws;     // NN*MM fp16 (384KB)
  _Float16* Ph = Qh + NN * MM;        // NN*MM fp16 (384KB)

  precompute_kernel<<<NN, 128, 0, stream>>>(hidden, gt, We, be, W1, b1, Qh, Ph, out);
  pairmlp_max_kernel<<<NIGRP * JSPLIT, 64, 0, stream>>>(Qh, Ph, W2, b2, out);
}